// Round 8
// baseline (504.495 us; speedup 1.0000x reference)
//
#include <hip/hip_runtime.h>
#include <cmath>

#define EPSF 1.1920928955078125e-07f

constexpr int BB = 8192;
constexpr int MZ = 2000;
constexpr int NF = 2048;
constexpr int ROW_BLOCKS = 2048;   // 4 waves/block, 1 row per wave -> 8192 rows
constexpr int MG_BLOCKS = 1024;    // 16 float4 iters per thread
constexpr int MG_ITERS = (BB * NF / 4) / (MG_BLOCKS * 256);  // 16
constexpr int TOTAL_BLOCKS = ROW_BLOCKS + MG_BLOCKS;         // 3072
constexpr float W_INT = 0.1f, W_PROB = 0.3f, W_WS = 0.5f, W_MORGAN = 0.1f;
constexpr float POS_W = 5.0f;

// d_ws layout (floats):
//   pb[k][row], k=0..4 : per-row partials (5 * 8192)
//   pbm[w], w=0..4095  : morgan per-WAVE partials (no LDS reduce needed)
constexpr int PB_STRIDE = BB;
constexpr int PBM_OFF = 5 * BB;
constexpr int PBM_N = MG_BLOCKS * 4;  // 4096

// butterfly: every lane ends with the full 64-lane sum (no broadcast needed)
__device__ inline float waveAllSum(float v) {
#pragma unroll
  for (int off = 1; off < 64; off <<= 1) v += __shfl_xor(v, off, 64);
  return v;
}

__device__ inline double waveReduceD(double v) {
#pragma unroll
  for (int off = 32; off > 0; off >>= 1) v += __shfl_down(v, off, 64);
  return v;
}

// natives: v_exp_f32 / v_log_f32 / v_rcp_f32 — ~1ulp, threshold 1.9e-2
__device__ inline float bceFast(float x, float y) {
  const float em = __expf(-fabsf(x));
  return fmaxf(x, 0.f) - x * y + __logf(1.f + em);
}

// One WAVE processes one full row: lane owns contiguous elems [lane*32, lane*32+32).
// 2000 = 62*32 + 16; 2000 % 4 == 0 so every float4 group is fully valid or
// fully out-of-range (no partial groups). Zero barriers, zero LDS.
__device__ void rowWave(int row,
                        const float* __restrict__ pi, const float* __restrict__ pl,
                        const float* __restrict__ ti, const float* __restrict__ tp,
                        float* __restrict__ pb) {
  const int lane = threadIdx.x & 63;
  const int cbase = lane * 32;
  const long base = (long)row * MZ + cbase;

  float a[32], b[32];
  float s_bce = 0.f, s_sq = 0.f, s_iw = 0.f, la = 0.f, lb = 0.f;

#pragma unroll
  for (int g = 0; g < 8; ++g) {
    const int e0 = cbase + g * 4;
    if (e0 + 4 <= MZ) {
      const float4 vpi = *(const float4*)(pi + base + g * 4);
      const float4 vpl = *(const float4*)(pl + base + g * 4);
      const float4 vti = *(const float4*)(ti + base + g * 4);
      const float4 vtp = *(const float4*)(tp + base + g * 4);
      const float xpi[4] = {vpi.x, vpi.y, vpi.z, vpi.w};
      const float xpl[4] = {vpl.x, vpl.y, vpl.z, vpl.w};
      const float xti[4] = {vti.x, vti.y, vti.z, vti.w};
      const float xtp[4] = {vtp.x, vtp.y, vtp.z, vtp.w};
#pragma unroll
      for (int k = 0; k < 4; ++k) {
        const float x = xpl[k];
        const float y = xtp[k];
        const float em = __expf(-fabsf(x));   // shared by bce + sigmoid
        const float bce = fmaxf(x, 0.f) - x * y + __logf(1.f + em);
        const bool pos = (y > 0.5f);
        s_bce += bce * (pos ? POS_W : 1.f);
        const float d = xpi[k] - xti[k];
        if (pos) { s_sq = fmaf(d, d, s_sq); s_iw += 1.f; }
        const float inv = __builtin_amdgcn_rcpf(1.f + em);
        const float sig = (x >= 0.f) ? inv : em * inv;
        const float av = fmaxf(xpi[k], 0.f) * sig;
        const float bv = xti[k] * y;
        a[g * 4 + k] = av; b[g * 4 + k] = bv;
        la += av; lb += bv;
      }
    } else {
#pragma unroll
      for (int k = 0; k < 4; ++k) { a[g * 4 + k] = 0.f; b[g * 4 + k] = 0.f; }
    }
  }

  // five row-sums, all lanes get totals (6 shfl_xor each)
  la = waveAllSum(la);
  lb = waveAllSum(lb);
  s_bce = waveAllSum(s_bce);
  s_sq = waveAllSum(s_sq);
  s_iw = waveAllSum(s_iw);
  if (lane == 0) {
    pb[0 * PB_STRIDE + row] = s_bce;
    pb[1 * PB_STRIDE + row] = s_sq;
    pb[2 * PB_STRIDE + row] = s_iw;
  }

  // jnp's double renormalization, analytically
  const float s1 = la, st1 = lb;
  const float s2 = s1 / (s1 + EPSF);
  const float scaleP = 1.f / ((s1 + EPSF) * (s2 + EPSF));
  const float st2 = st1 / (st1 + EPSF);
  const float scaleQ = 1.f / ((st1 + EPSF) * (st2 + EPSF));

  // in-register inclusive prefix over this lane's 32-elem chunk
  float run = 0.f;
#pragma unroll
  for (int j = 0; j < 32; ++j) {
    run += a[j] * scaleP - b[j] * scaleQ;
    a[j] = run;
  }

  // wave-level scan of chunk totals (6 shfl_up, no LDS)
  float sc = run;
#pragma unroll
  for (int off = 1; off < 64; off <<= 1) {
    const float t = __shfl_up(sc, off, 64);
    if (lane >= off) sc += t;
  }
  const float excl = sc - run;

  // |cdf| sum excluding last grid point (gidx == MZ-1); invalid gidx >= MZ also excluded
  float labs = 0.f;
#pragma unroll
  for (int j = 0; j < 32; ++j) {
    if (cbase + j < MZ - 1) labs += fabsf(excl + a[j]);
  }
  labs = waveAllSum(labs);

  if (lane == 0) {
    const float w1 = labs * (1.f / (1999.0f + EPSF));
    const float psum = s2 / (s2 + EPSF);
    const float qsum = st2 / (st2 + EPSF);
    const float valid = (qsum > EPSF) ? 1.f : 0.f;
    const float per = (psum > EPSF) ? w1 : 1.f;
    pb[3 * PB_STRIDE + row] = per * valid;
    pb[4 * PB_STRIDE + row] = valid;
  }
}

// morgan: pure grid-stride streaming; per-wave partial store (no LDS, no barrier)
__device__ void morganBlock(int mb, const float* __restrict__ x,
                            const int* __restrict__ y, float* __restrict__ pbm) {
  const int wid = threadIdx.x >> 6;
  const int lane = threadIdx.x & 63;
  float ls = 0.f;
  long i = (long)mb * 256 + threadIdx.x;
  const long stride = (long)MG_BLOCKS * 256;
#pragma unroll 4
  for (int it = 0; it < MG_ITERS; ++it, i += stride) {
    const float4 xv = ((const float4*)x)[i];
    const int4 yv = ((const int4*)y)[i];
    ls += bceFast(xv.x, (float)yv.x);
    ls += bceFast(xv.y, (float)yv.y);
    ls += bceFast(xv.z, (float)yv.z);
    ls += bceFast(xv.w, (float)yv.w);
  }
  ls = waveAllSum(ls);
  if (lane == 0) pbm[mb * 4 + wid] = ls;
}

// 3072 blocks, groups of 3 = 2 row-blocks (4 rows each) + 1 morgan block
__global__ __launch_bounds__(256) void fused_kernel(
    const float* __restrict__ pi, const float* __restrict__ pl,
    const float* __restrict__ ti, const float* __restrict__ tp,
    const float* __restrict__ mx, const int* __restrict__ my,
    float* __restrict__ ws) {
  const int q = blockIdx.x / 3;
  const int r = blockIdx.x % 3;
  if (r < 2) {
    const int rb = q * 2 + r;                    // [0, 2048)
    const int row = rb * 4 + (threadIdx.x >> 6); // one row per wave
    rowWave(row, pi, pl, ti, tp, ws);
  } else {
    morganBlock(q, mx, my, ws + PBM_OFF);
  }
}

__global__ __launch_bounds__(1024) void reduce_finalize_kernel(
    const float* __restrict__ ws, float* __restrict__ out) {
  __shared__ double red[16][8];
  const int tid = threadIdx.x;
  const int lane = tid & 63, wid = tid >> 6;

  double acc[6] = {0, 0, 0, 0, 0, 0};
#pragma unroll
  for (int k = 0; k < 5; ++k) {
    const float4* v = (const float4*)(ws + k * PB_STRIDE);
    for (int i = tid; i < BB / 4; i += 1024) {
      const float4 f = v[i];
      acc[k] += (double)f.x + (double)f.y + (double)f.z + (double)f.w;
    }
  }
  {
    const float4* v = (const float4*)(ws + PBM_OFF);
    for (int i = tid; i < PBM_N / 4; i += 1024) {
      const float4 f = v[i];
      acc[5] += (double)f.x + (double)f.y + (double)f.z + (double)f.w;
    }
  }

#pragma unroll
  for (int k = 0; k < 6; ++k) acc[k] = waveReduceD(acc[k]);
  if (lane == 0) {
#pragma unroll
    for (int k = 0; k < 6; ++k) red[wid][k] = acc[k];
  }
  __syncthreads();
  if (tid == 0) {
    double t[6];
#pragma unroll
    for (int k = 0; k < 6; ++k) {
      double s = 0.0;
      for (int w = 0; w < 16; ++w) s += red[w][k];
      t[k] = s;
    }
    const double prob = t[0] / ((double)BB * (double)MZ);
    const double inten = t[1] / (t[2] + (double)EPSF);
    const double nv = t[4];
    const double ws_loss = (nv > 0.0) ? (t[3] / fmax(nv, 1.0)) : 0.0;
    const double morgan = t[5] / ((double)BB * (double)NF);
    double tot = (double)W_PROB * prob + (double)W_INT * inten +
                 (double)W_WS * ws_loss + (double)W_MORGAN * morgan;
    float r = (float)tot;
    if (isnan(r) || isinf(r)) r = 100000.0f;
    out[0] = r;
  }
}

extern "C" void kernel_launch(void* const* d_in, const int* in_sizes, int n_in,
                              void* d_out, int out_size, void* d_ws, size_t ws_size,
                              hipStream_t stream) {
  const float* pred_int = (const float*)d_in[0];
  const float* pred_pl  = (const float*)d_in[1];
  const float* pred_mg  = (const float*)d_in[2];
  const float* true_int = (const float*)d_in[3];
  const float* true_pr  = (const float*)d_in[4];
  const int*   true_mg  = (const int*)d_in[5];
  float* ws = (float*)d_ws;

  fused_kernel<<<TOTAL_BLOCKS, 256, 0, stream>>>(
      pred_int, pred_pl, true_int, true_pr, pred_mg, true_mg, ws);
  reduce_finalize_kernel<<<1, 1024, 0, stream>>>(ws, (float*)d_out);
}

// Round 9
// 356.789 us; speedup vs baseline: 1.4140x; 1.4140x over previous
//
#include <hip/hip_runtime.h>
#include <cmath>

#define EPSF 1.1920928955078125e-07f

constexpr int BB = 8192;
constexpr int MZ = 2000;
constexpr int NF = 2048;
constexpr int MG_BLOCKS = 2048;
constexpr int MG_ITERS = (BB * NF / 4) / (MG_BLOCKS * 256);  // 8
constexpr int FUSED_BLOCKS = (BB / 4) * 5;                   // 10240: 4 row + 1 morgan per group
constexpr float W_INT = 0.1f, W_PROB = 0.3f, W_WS = 0.5f, W_MORGAN = 0.1f;
constexpr float POS_W = 5.0f;

// d_ws layout (floats). Per-(row,wave) partials avoid any second block barrier.
constexpr int OFF_BCE   = 0;           // [BB*4] bce*w   per (row,wave)
constexpr int OFF_SQ    = 32768;       // [BB*4] sq      per (row,wave)
constexpr int OFF_IW    = 65536;       // [BB*4] iw      per (row,wave)
constexpr int OFF_WS    = 98304;       // [BB*4] ws contrib per (row,wave)
constexpr int OFF_VALID = 131072;      // [BB]   valid   per row
constexpr int OFF_MG    = 139264;      // [MG_BLOCKS*4] morgan per (block,wave)
// total 147456 floats = 576 KB

__device__ inline float waveReduce(float v) {
#pragma unroll
  for (int off = 32; off > 0; off >>= 1) v += __shfl_down(v, off, 64);
  return v;
}

__device__ inline double waveReduceD(double v) {
#pragma unroll
  for (int off = 32; off > 0; off >>= 1) v += __shfl_down(v, off, 64);
  return v;
}

// natives: v_exp_f32 / v_log_f32 / v_rcp_f32 — ~1ulp, threshold 1.9e-2
__device__ inline float bceFast(float x, float y) {
  const float em = __expf(-fabsf(x));
  return fmaxf(x, 0.f) - x * y + __logf(1.f + em);
}

// One block = one row, thread owns 8 contiguous elems (coalesced float4 x2
// per array). Exactly ONE barrier: only the two wave scan-totals cross waves.
__device__ void rowBody(int row,
                        const float* __restrict__ pi, const float* __restrict__ pl,
                        const float* __restrict__ ti, const float* __restrict__ tp,
                        float* __restrict__ pb) {
  __shared__ float lds[4][2];
  const int tid = threadIdx.x;
  const int lane = tid & 63;
  const int wid = tid >> 6;
  const int i0 = tid * 8;
  const bool act = (i0 + 8 <= MZ);  // threads 0..249

  float A[8], B[8];              // in-thread inclusive prefixes (unnormalized)
  float s_bce = 0.f, s_sq = 0.f, s_iw = 0.f;
  float accA = 0.f, accB = 0.f;

  if (act) {
    const long base = (long)row * MZ + i0;
    const float4 vpi0 = *(const float4*)(pi + base), vpi1 = *(const float4*)(pi + base + 4);
    const float4 vpl0 = *(const float4*)(pl + base), vpl1 = *(const float4*)(pl + base + 4);
    const float4 vti0 = *(const float4*)(ti + base), vti1 = *(const float4*)(ti + base + 4);
    const float4 vtp0 = *(const float4*)(tp + base), vtp1 = *(const float4*)(tp + base + 4);
    const float xpi[8] = {vpi0.x, vpi0.y, vpi0.z, vpi0.w, vpi1.x, vpi1.y, vpi1.z, vpi1.w};
    const float xpl[8] = {vpl0.x, vpl0.y, vpl0.z, vpl0.w, vpl1.x, vpl1.y, vpl1.z, vpl1.w};
    const float xti[8] = {vti0.x, vti0.y, vti0.z, vti0.w, vti1.x, vti1.y, vti1.z, vti1.w};
    const float xtp[8] = {vtp0.x, vtp0.y, vtp0.z, vtp0.w, vtp1.x, vtp1.y, vtp1.z, vtp1.w};
#pragma unroll
    for (int j = 0; j < 8; ++j) {
      const float x = xpl[j];
      const float y = xtp[j];
      const float em = __expf(-fabsf(x));   // shared by bce + sigmoid
      const float bce = fmaxf(x, 0.f) - x * y + __logf(1.f + em);
      const bool pos = (y > 0.5f);
      s_bce += bce * (pos ? POS_W : 1.f);
      const float d = xpi[j] - xti[j];
      if (pos) { s_sq = fmaf(d, d, s_sq); s_iw += 1.f; }
      const float inv = __builtin_amdgcn_rcpf(1.f + em);
      const float sig = (x >= 0.f) ? inv : em * inv;
      const float av = fmaxf(xpi[j], 0.f) * sig;
      const float bv = xti[j] * y;
      accA += av; A[j] = accA;    // prefix of a (scale applied post-barrier)
      accB += bv; B[j] = accB;    // prefix of b
    }
  } else {
#pragma unroll
    for (int j = 0; j < 8; ++j) { A[j] = 0.f; B[j] = 0.f; }
  }

  // wave-level inclusive scans of thread totals (6 shfl_up each, independent)
  float scA = accA, scB = accB;
#pragma unroll
  for (int off = 1; off < 64; off <<= 1) {
    const float tA = __shfl_up(scA, off, 64);
    const float tB = __shfl_up(scB, off, 64);
    if (lane >= off) { scA += tA; scB += tB; }
  }
  const float wexA = scA - accA;            // wave-exclusive offsets
  const float wexB = scB - accB;
  const float wtA = __shfl(scA, 63, 64);    // wave totals
  const float wtB = __shfl(scB, 63, 64);

  // per-wave reduces for the three streaming partials -> straight to global
  s_bce = waveReduce(s_bce);
  s_sq  = waveReduce(s_sq);
  s_iw  = waveReduce(s_iw);
  if (lane == 0) {
    pb[OFF_BCE + row * 4 + wid] = s_bce;
    pb[OFF_SQ  + row * 4 + wid] = s_sq;
    pb[OFF_IW  + row * 4 + wid] = s_iw;
    lds[wid][0] = wtA; lds[wid][1] = wtB;
  }
  __syncthreads();  // the ONLY barrier

  // every thread independently derives row sums + its scan offsets
  float s1 = 0.f, st1 = 0.f, rowAoff = 0.f, rowBoff = 0.f;
#pragma unroll
  for (int w = 0; w < 4; ++w) {
    const float aw = lds[w][0], bw = lds[w][1];
    s1 += aw; st1 += bw;
    if (w < wid) { rowAoff += aw; rowBoff += bw; }
  }

  // jnp's double renormalization, analytically
  const float s2 = s1 / (s1 + EPSF);
  const float scaleP = 1.f / ((s1 + EPSF) * (s2 + EPSF));
  const float st2 = st1 / (st1 + EPSF);
  const float scaleQ = 1.f / ((st1 + EPSF) * (st2 + EPSF));

  const float exA = rowAoff + wexA;
  const float exB = rowBoff + wexB;
  float labs = 0.f;
#pragma unroll
  for (int j = 0; j < 8; ++j) {
    if (i0 + j < MZ - 1)  // positions 0..1998; inactive tails auto-excluded
      labs += fabsf(scaleP * (exA + A[j]) - scaleQ * (exB + B[j]));
  }
  labs = waveReduce(labs);  // per-wave partial of the |cdf| sum

  if (lane == 0) {
    const float psum = s2 / (s2 + EPSF);
    const float qsum = st2 / (st2 + EPSF);
    const float valid = (qsum > EPSF) ? 1.f : 0.f;
    // decomposition: sum over waves == valid * (psum>EPS ? w1 : 1.0)
    const float contrib =
        valid * ((psum > EPSF) ? labs * (1.f / (1999.0f + EPSF))
                               : (wid == 0 ? 1.f : 0.f));
    pb[OFF_WS + row * 4 + wid] = contrib;
    if (wid == 0) pb[OFF_VALID + row] = valid;
  }
}

// morgan: pure streaming, per-wave partial stores — zero LDS, zero barriers
__device__ void morganBody(int mb, const float* __restrict__ x,
                           const int* __restrict__ y, float* __restrict__ pbm) {
  const int lane = threadIdx.x & 63, wid = threadIdx.x >> 6;
  float ls = 0.f;
  long i = (long)mb * 256 + threadIdx.x;
  const long stride = (long)MG_BLOCKS * 256;
#pragma unroll
  for (int it = 0; it < MG_ITERS; ++it, i += stride) {
    const float4 xv = ((const float4*)x)[i];
    const int4 yv = ((const int4*)y)[i];
    ls += bceFast(xv.x, (float)yv.x);
    ls += bceFast(xv.y, (float)yv.y);
    ls += bceFast(xv.z, (float)yv.z);
    ls += bceFast(xv.w, (float)yv.w);
  }
  ls = waveReduce(ls);
  if (lane == 0) pbm[mb * 4 + wid] = ls;
}

// 10240 blocks: groups of 5 = 4 row-blocks + 1 morgan block (R5's proven mix)
__global__ __launch_bounds__(256) void fused_kernel(
    const float* __restrict__ pi, const float* __restrict__ pl,
    const float* __restrict__ ti, const float* __restrict__ tp,
    const float* __restrict__ mx, const int* __restrict__ my,
    float* __restrict__ ws) {
  const int q = blockIdx.x / 5;
  const int r = blockIdx.x % 5;
  if (r < 4) {
    rowBody(q * 4 + r, pi, pl, ti, tp, ws);
  } else {
    morganBody(q, mx, my, ws + OFF_MG);
  }
}

__global__ __launch_bounds__(1024) void reduce_finalize_kernel(
    const float* __restrict__ ws, float* __restrict__ out) {
  __shared__ double red[16][8];
  const int tid = threadIdx.x;
  const int lane = tid & 63, wid = tid >> 6;

  // segment order matches acc index: bce, sq, iw, wscontrib, valid, morgan
  const int offs[6] = {OFF_BCE, OFF_SQ, OFF_IW, OFF_WS, OFF_VALID, OFF_MG};
  const int lens[6] = {BB * 4, BB * 4, BB * 4, BB * 4, BB, MG_BLOCKS * 4};

  double acc[6] = {0, 0, 0, 0, 0, 0};
#pragma unroll
  for (int k = 0; k < 6; ++k) {
    const float4* v = (const float4*)(ws + offs[k]);
    const int n4 = lens[k] / 4;
    for (int i = tid; i < n4; i += 1024) {
      const float4 f = v[i];
      acc[k] += (double)f.x + (double)f.y + (double)f.z + (double)f.w;
    }
  }

#pragma unroll
  for (int k = 0; k < 6; ++k) acc[k] = waveReduceD(acc[k]);
  if (lane == 0) {
#pragma unroll
    for (int k = 0; k < 6; ++k) red[wid][k] = acc[k];
  }
  __syncthreads();
  if (tid == 0) {
    double t[6];
#pragma unroll
    for (int k = 0; k < 6; ++k) {
      double s = 0.0;
      for (int w = 0; w < 16; ++w) s += red[w][k];
      t[k] = s;
    }
    const double prob = t[0] / ((double)BB * (double)MZ);
    const double inten = t[1] / (t[2] + (double)EPSF);
    const double nv = t[4];
    const double ws_loss = (nv > 0.0) ? (t[3] / fmax(nv, 1.0)) : 0.0;
    const double morgan = t[5] / ((double)BB * (double)NF);
    double tot = (double)W_PROB * prob + (double)W_INT * inten +
                 (double)W_WS * ws_loss + (double)W_MORGAN * morgan;
    float r = (float)tot;
    if (isnan(r) || isinf(r)) r = 100000.0f;
    out[0] = r;
  }
}

extern "C" void kernel_launch(void* const* d_in, const int* in_sizes, int n_in,
                              void* d_out, int out_size, void* d_ws, size_t ws_size,
                              hipStream_t stream) {
  const float* pred_int = (const float*)d_in[0];
  const float* pred_pl  = (const float*)d_in[1];
  const float* pred_mg  = (const float*)d_in[2];
  const float* true_int = (const float*)d_in[3];
  const float* true_pr  = (const float*)d_in[4];
  const int*   true_mg  = (const int*)d_in[5];
  float* ws = (float*)d_ws;

  fused_kernel<<<FUSED_BLOCKS, 256, 0, stream>>>(
      pred_int, pred_pl, true_int, true_pr, pred_mg, true_mg, ws);
  reduce_finalize_kernel<<<1, 1024, 0, stream>>>(ws, (float*)d_out);
}